// Round 11
// baseline (715.133 us; speedup 1.0000x reference)
//
#include <hip/hip_runtime.h>

#define GN    128
#define GBIG  1.0e5f
#define NITER 128

// Padded layout: x pitch 128, y and z padded to 130 with BIG boundary planes.
#define PPY     130
#define PITCH_Y 128
#define PITCH_Z (128 * 130)
#define PADDED_TOTAL (130 * 130 * 128)

// Wave-tile lattice: each WAVE owns a 128 x 2 x 1 tile (2 rows, ONE plane).
// 64 x 128 = 8192 tiles.  Block = 4 waves (2y x 2z tiles); grid 32 x 64 =
// 2048 blocks = 8 blocks/CU = 32 waves/CU (full occupancy; VGPR<=64 enforced).
#define NTY  64
#define NTZ  128
#define NTILE (NTY * NTZ)

typedef float fx4 __attribute__((ext_vector_type(4)));
typedef int   ix4 __attribute__((ext_vector_type(4)));

// ---------------------------------------------------------------------------
// init: padded uA, uB, fP + per-tile inbox lines (64B each).
// inbox[t][0..3] = iter published by the {-y,+y,-z,+z} producer of tile t.
// Missing producer => NITER (satisfies any target).
// ---------------------------------------------------------------------------
__global__ __launch_bounds__(256) void eik_init(const float* __restrict__ u0,
                                                const float* __restrict__ f,
                                                float* __restrict__ uA,
                                                float* __restrict__ uB,
                                                float* __restrict__ fP,
                                                int* __restrict__ inbox) {
    const int i = blockIdx.x * 256 + threadIdx.x;
    if (i < NTILE * 16) {
        const int t = i >> 4, d = i & 15;
        const int ly = t & (NTY - 1), lz = t >> 6;
        int v = 0;
        if ((d == 0 && ly == 0) || (d == 1 && ly == NTY - 1) ||
            (d == 2 && lz == 0) || (d == 3 && lz == NTZ - 1))
            v = NITER;
        inbox[i] = v;
    }
    if (i >= PADDED_TOTAL) return;
    const int x = i & 127;
    const int r = i >> 7;          // r = z*130 + y
    const int y = r % 130;
    const int z = r / 130;
    float uv = GBIG, fv = 0.0f;
    if (y >= 1 && y <= GN && z >= 1 && z <= GN) {
        const int src = ((z - 1) * GN + (y - 1)) * GN + x;
        uv = u0[src];
        fv = f[src];
    }
    uA[i] = uv;
    uB[i] = uv;
    fP[i] = fv;
}

// fh2 = fh*fh hoisted (loop-invariant per cell).
__device__ __forceinline__ float eik_solve(float ax, float ay, float az,
                                           float fh, float fh2, float uc) {
    const float a1 = fminf(fminf(ax, ay), az);
    const float a3 = fmaxf(fmaxf(ax, ay), az);
    const float a2 = fmaxf(fminf(fmaxf(ax, ay), az), fminf(ax, ay));
    const float x1 = a1 + fh;
    const float d12 = a1 - a2;
    const float disc2 = fh2 + fh2 - d12 * d12;
    const float x2 = 0.5f * (a1 + a2 + sqrtf(fmaxf(disc2, 0.0f)));
    const float s = a1 + a2 + a3;
    const float q = a1 * a1 + a2 * a2 + a3 * a3;
    const float disc3 = s * s - 3.0f * (q - fh2);
    const float x3 = (s + sqrtf(fmaxf(disc3, 0.0f))) * (1.0f / 3.0f);
    const float xv = (x1 <= a2) ? x1 : ((x2 <= a3) ? x2 : x3);
    return fminf(uc, xv);
}

// FLAT addressing throughout (saddr "s"-form miscompiled in round 7).
__device__ __forceinline__ void pubp(int* p, int val) {
    asm volatile("global_store_dword %0, %1, off sc1"
                 :: "v"(p), "v"(val) : "memory");
}
__device__ __forceinline__ void stS(float* p, fx4 v) {
    asm volatile("global_store_dwordx4 %0, %1, off sc1"
                 :: "v"(p), "v"(v) : "memory");
}

// ---------------------------------------------------------------------------
// persistent kernel, plain launch (graph-capturable).  R11: test the ONLY
// scaling law the 10-round ledger supports.  R5 vs R4: halve waves + double
// per-wave work -> period exactly doubles (4.7 -> 9.4 us).  Every other
// variable (sync topology, scope, spin cadence, instruction diet) left the
// ~5.4us period invariant.  So go the other way: 8192 wave-tiles of 128x2x1
// (half the per-wave chain of R8's 128x2x2) at 32 waves/CU (double R8's
// occupancy).  Per-wave round: poll 1 line -> 3 halo loads -> 4 solves ->
// 1 store -> drain -> 4 flag pubs.  No __syncthreads.
//
// Protocol (unchanged, proven absmax 0.5 in R8-R10): inbox slot >= i-1
// gates both RAW and WAR of the ping-pong buffers.  flag=i implies round-i
// stores drained (vmcnt0 before pub) and round-i reads done.  Per-face
// direction culling: skip waiting on faces whose adjacent cells are all
// inactive (d > i) — act-culled cells are never stored, nothing stale read.
// Buffer parity via byte-offset add from uA-based pointers (keeps VGPR<=64
// for 8 blocks/CU residency; enforced by __launch_bounds__(256,8) and the
// host-side occupancy gate).
// ---------------------------------------------------------------------------
__global__ __launch_bounds__(256, 8) void eik_persist(float* __restrict__ uA,
                                                      float* __restrict__ uB,
                                                      const float* __restrict__ fP,
                                                      float* __restrict__ out,
                                                      int* __restrict__ inbox) {
    const int tid  = threadIdx.x;      // 0..255
    const int w    = tid >> 6;         // wave 0..3
    const int lane = tid & 63;
    const int r    = lane >> 5;        // row within tile (0/1)
    const int sub  = lane & 31;        // x-group
    const int x0   = sub * 4;

    // wave-tile coords: block = 2y x 2z tiles
    const int ly = blockIdx.y * 2 + (w & 1);   // 0..63
    const int lz = blockIdx.z * 2 + (w >> 1);  // 0..127
    const int gy0 = ly * 2;                    // rows gy0, gy0+1
    const int gy  = gy0 + r;
    const int gz  = lz;                        // single plane

    // per-cell act distance (exact active-set cull)
    const int dxm = (x0 <= 64 && 64 <= x0 + 3) ? 0
                                               : min(abs(x0 - 64), abs(x0 + 3 - 64));
    const int dz = abs(gz - 64);
    const int d0 = dxm + abs(gy - 64) + dz;

    // tile/face distances (x spans the source column -> +0)
    const int dymin = (gy0 > 64) ? (gy0 - 64) : ((gy0 + 1 < 64) ? (64 - (gy0 + 1)) : 0);
    const int start = max(1, dymin + dz);
    const int dYm = abs(gy0 - 64) + dz;          // face row gy0     (slot 0)
    const int dYp = abs(gy0 + 1 - 64) + dz;      // face row gy0+1   (slot 1)
    const int dZf = dymin + dz;                  // z faces = whole tile (2,3)

    const int idx = lz * NTY + ly;
    int* inb = inbox + idx * 16;                 // own 64B line
    int* pYp = inbox + (idx + 1) * 16 + 0;       // +y dependent's -y slot
    int* pYm = inbox + (idx - 1) * 16 + 1;       // -y dependent's +y slot
    int* pZp = inbox + (idx + NTY) * 16 + 2;     // +z dependent's -z slot
    int* pZm = inbox + (idx - NTY) * 16 + 3;     // -z dependent's +z slot

    if (lane == 0 && start > 1) {   // pre-publish: u_{start-1} == u_0 here
        const int pv = start - 1;
        if (ly < NTY - 1) pubp(pYp, pv);
        if (ly > 0)       pubp(pYm, pv);
        if (lz < NTZ - 1) pubp(pZp, pv);
        if (lz > 0)       pubp(pZm, pv);
    }

    const int base = ((gz + 1) * PPY + (gy + 1)) * PITCH_Y + x0;
    const int rowoff = (r == 0) ? -PITCH_Y : PITCH_Y;  // outer y-halo row

    // uA-based pointers; uB set = +DB bytes (launcher guarantees uB=uA+PADDED_TOTAL)
    const char* pAy  = (const char*)(uA + base + rowoff);
    const char* pAzm = (const char*)(uA + base - PITCH_Z);
    const char* pAzp = (const char*)(uA + base + PITCH_Z);
    char*       pAd  = (char*)(uA + base);
    const size_t DB = (size_t)PADDED_TOTAL * sizeof(float);

    fx4 c0 = *(const fx4*)(uA + base);
    const fx4 f0 = *(const fx4*)(fP + base);
    const fx4 ff0 = f0 * f0;

    for (int i = start; i <= NITER; ++i) {
        // ---- single-load inbox spin, per-direction targets ----
        const int tgt = i - 1;
        const int tYm = (dYm <= i) ? tgt : -0x40000000;
        const int tYp = (dYp <= i) ? tgt : -0x40000000;
        const int tZf = (dZf <= i) ? tgt : -0x40000000;
        ix4 v;
        for (;;) {
            asm volatile("global_load_dwordx4 %0, %1, off sc1\n\t"
                         "s_waitcnt vmcnt(0)"
                         : "=&v"(v) : "v"(inb) : "memory");
            if (v.x >= tYm && v.y >= tYp && v.z >= tZf && v.w >= tZf) break;
            const int lag = max(max(tYm - v.x, tYp - v.y),
                                max(tZf - v.z, tZf - v.w));
            if (lag > 2) __builtin_amdgcn_s_sleep(64);
            else         __builtin_amdgcn_s_sleep(16);
        }

        // ---- inner y-row exchange via shfl_xor(32); x via row shuffles ----
        fx4 o0;
        o0.x = __shfl_xor(c0.x, 32); o0.y = __shfl_xor(c0.y, 32);
        o0.z = __shfl_xor(c0.z, 32); o0.w = __shfl_xor(c0.w, 32);
        float xm0 = __shfl_up(c0.w, 1);   if (sub == 0)  xm0 = GBIG;
        float xp0 = __shfl_down(c0.x, 1); if (sub == 31) xp0 = GBIG;

        if (d0 <= i) {
            const size_t rb = (i & 1) ? 0 : DB;   // odd reads uA, even reads uB
            fx4 yh0, zm, zp;
            asm volatile(
                "global_load_dwordx4 %0, %3, off sc1\n\t"
                "global_load_dwordx4 %1, %4, off sc1\n\t"
                "global_load_dwordx4 %2, %5, off sc1\n\t"
                "s_waitcnt vmcnt(0)"
                : "=&v"(yh0), "=&v"(zm), "=&v"(zp)
                : "v"(pAy + rb), "v"(pAzm + rb), "v"(pAzp + rb)
                : "memory");

            const fx4 ya0 = (r == 0) ? yh0 : o0;   // -y side
            const fx4 yb0 = (r == 0) ? o0  : yh0;  // +y side

            fx4 n0;
            n0.x = eik_solve(fminf(xm0,  c0.y), fminf(ya0.x, yb0.x),
                             fminf(zm.x, zp.x), f0.x, ff0.x, c0.x);
            n0.y = eik_solve(fminf(c0.x, c0.z), fminf(ya0.y, yb0.y),
                             fminf(zm.y, zp.y), f0.y, ff0.y, c0.y);
            n0.z = eik_solve(fminf(c0.y, c0.w), fminf(ya0.z, yb0.z),
                             fminf(zm.z, zp.z), f0.z, ff0.z, c0.z);
            n0.w = eik_solve(fminf(c0.z, xp0),  fminf(ya0.w, yb0.w),
                             fminf(zm.w, zp.w), f0.w, ff0.w, c0.w);
            c0 = n0;
            if (i < NITER) {
                const size_t wb = (i & 1) ? DB : 0;
                stS((float*)(pAd + wb), c0);
            }
        }

        if (i < NITER) {
            asm volatile("s_waitcnt vmcnt(0)" ::: "memory");  // own-wave drain
            if (lane == 0) {
                if (ly > 0)       pubp(pYm, i);
                if (ly < NTY - 1) pubp(pYp, i);
                if (lz > 0)       pubp(pZm, i);
                if (lz < NTZ - 1) pubp(pZp, i);
            }
        }
    }

    // fused extract: compact 128^3 output straight from registers
    *(fx4*)(out + (gz * GN + gy) * GN + x0) = c0;
}

// ---------------------------------------------------------------------------
// fallback path (proven 128-launch structure) if occupancy check fails
// ---------------------------------------------------------------------------
__global__ __launch_bounds__(256) void eik_step(const float* __restrict__ uin,
                                                const float* __restrict__ fP,
                                                float* __restrict__ uout,
                                                int iter) {
    const int lx = threadIdx.x;
    const int gy = blockIdx.y * 8 + threadIdx.y;
    const int gz = blockIdx.z;
    const int x0 = 4 * lx;
    const int dxm = (x0 <= 64 && 64 <= x0 + 3)
                        ? 0
                        : min(abs(x0 - 64), abs(x0 + 3 - 64));
    const int d = dxm + abs(gy - 64) + abs(gz - 64);
    if (d > iter) return;

    const int y = gy + 1;
    const int z = gz + 1;
    const int base = (z * PPY + y) * PITCH_Y + x0;

    const float4 c  = *(const float4*)(uin + base);
    float xm_s = uin[base - 1];
    float xp_s = uin[base + 4];
    if (lx == 0)  xm_s = GBIG;
    if (lx == 31) xp_s = GBIG;
    const float4 ym = *(const float4*)(uin + base - PITCH_Y);
    const float4 yp = *(const float4*)(uin + base + PITCH_Y);
    const float4 zm = *(const float4*)(uin + base - PITCH_Z);
    const float4 zp = *(const float4*)(uin + base + PITCH_Z);
    const float4 f4 = *(const float4*)(fP + base);

    float4 res;
    res.x = eik_solve(fminf(xm_s, c.y), fminf(ym.x, yp.x), fminf(zm.x, zp.x), f4.x, f4.x * f4.x, c.x);
    res.y = eik_solve(fminf(c.x, c.z), fminf(ym.y, yp.y), fminf(zm.y, zp.y), f4.y, f4.y * f4.y, c.y);
    res.z = eik_solve(fminf(c.y, c.w), fminf(ym.z, yp.z), fminf(zm.z, zp.z), f4.z, f4.z * f4.z, c.z);
    res.w = eik_solve(fminf(c.z, xp_s), fminf(ym.w, yp.w), fminf(zm.w, zp.w), f4.w, f4.w * f4.w, c.w);

    *(float4*)(uout + base) = res;
}

__global__ __launch_bounds__(256) void eik_extract(const float* __restrict__ uf,
                                                   float* __restrict__ out) {
    const int j = blockIdx.x * 256 + threadIdx.x;
    const int x4 = j & 31;
    const int y  = (j >> 5) & 127;
    const int z  = j >> 12;
    const float4 v =
        *(const float4*)(uf + ((z + 1) * PPY + (y + 1)) * PITCH_Y + 4 * x4);
    *(float4*)(out + 4 * j) = v;
}

extern "C" void kernel_launch(void* const* d_in, const int* in_sizes, int n_in,
                              void* d_out, int out_size, void* d_ws, size_t ws_size,
                              hipStream_t stream) {
    const float* u0 = (const float*)d_in[0];
    const float* f  = (const float*)d_in[1];
    float* out = (float*)d_out;

    float* uA = (float*)d_ws;                    // 8.65 MB each
    float* uB = uA + PADDED_TOTAL;               // MUST stay uA+PADDED_TOTAL (DB trick)
    float* fP = uB + PADDED_TOTAL;
    int* inbox = (int*)(fP + PADDED_TOTAL);      // 512 KB wave-tile inbox lines

    {
        const int nb = (PADDED_TOTAL + 255) / 256;
        eik_init<<<nb, 256, 0, stream>>>(u0, f, uA, uB, fP, inbox);
    }

    // Co-residency capacity check (host query, capture-safe, cached):
    // 2048 blocks / 256 CUs -> need >= 8 blocks/CU resident (VGPR <= 64).
    static int resident_ok = -1;
    if (resident_ok < 0) {
        int maxb = 0;
        hipError_t qe =
            hipOccupancyMaxActiveBlocksPerMultiprocessor(&maxb, eik_persist, 256, 0);
        resident_ok = (qe == hipSuccess && maxb >= 8) ? 1 : 0;
    }

    if (resident_ok) {
        eik_persist<<<dim3(1, 32, 64), 256, 0, stream>>>(uA, uB, fP, out, inbox);
        return;
    }

    // fallback: proven 128-launch ping-pong
    const dim3 block(32, 8, 1);
    const dim3 grid(1, 16, 128);
    for (int i = 1; i <= NITER; ++i) {
        const float* in = (i & 1) ? uA : uB;
        float* o        = (i & 1) ? uB : uA;
        eik_step<<<grid, block, 0, stream>>>(in, fP, o, i);
    }
    eik_extract<<<GN * GN * GN / 4 / 256, 256, 0, stream>>>(uA, out);
}

// Round 12
// 714.733 us; speedup vs baseline: 1.0006x; 1.0006x over previous
//
#include <hip/hip_runtime.h>

#define GN    128
#define GBIG  1.0e5f
#define NITER 128

// Padded layout: x pitch 128, y and z padded to 130 with BIG boundary planes.
#define PPY     130
#define PITCH_Y 128
#define PITCH_Z (128 * 130)
#define PADDED_TOTAL (130 * 130 * 128)

// Wave-tile lattice (R8 geometry): each WAVE owns 128 x 2 x 2.  64x64 tiles.
// Block = 4 waves (2y x 2z tiles); grid 32 x 32 = 1024 blocks, 4 blocks/CU.
#define NTY  64
#define NTZ  64
#define NTILE (NTY * NTZ)
#define LSTR (NTILE * 16)   // ints per inbox direction-plane

typedef float fx4 __attribute__((ext_vector_type(4)));

// ---------------------------------------------------------------------------
// init: padded uA, uB, fP + inbox: 4 direction-planes of 64B lines, ONE
// writer per line (the {-y,+y,-z,+z} producer of that tile).  Value layout:
// (xcc+1)<<16 | iter.  Missing producer => iter=NITER (xcc=0, never classed).
// ---------------------------------------------------------------------------
__global__ __launch_bounds__(256) void eik_init(const float* __restrict__ u0,
                                                const float* __restrict__ f,
                                                float* __restrict__ uA,
                                                float* __restrict__ uB,
                                                float* __restrict__ fP,
                                                int* __restrict__ inbox) {
    const int i = blockIdx.x * 256 + threadIdx.x;
    if (i < 4 * LSTR) {
        const int li = i >> 4;             // line index
        const int dir = li >> 12;          // NTILE = 2^12
        const int tl = li & (NTILE - 1);
        const int ly = tl & 63, lz = tl >> 6;
        int v = 0;
        if ((dir == 0 && ly == 0) || (dir == 1 && ly == NTY - 1) ||
            (dir == 2 && lz == 0) || (dir == 3 && lz == NTZ - 1))
            v = NITER;
        inbox[i] = v;
    }
    if (i >= PADDED_TOTAL) return;
    const int x = i & 127;
    const int r = i >> 7;          // r = z*130 + y
    const int y = r % 130;
    const int z = r / 130;
    float uv = GBIG, fv = 0.0f;
    if (y >= 1 && y <= GN && z >= 1 && z <= GN) {
        const int src = ((z - 1) * GN + (y - 1)) * GN + x;
        uv = u0[src];
        fv = f[src];
    }
    uA[i] = uv;
    uB[i] = uv;
    fP[i] = fv;
}

__device__ __forceinline__ float eik_solve(float ax, float ay, float az,
                                           float fh, float fh2, float uc) {
    const float a1 = fminf(fminf(ax, ay), az);
    const float a3 = fmaxf(fmaxf(ax, ay), az);
    const float a2 = fmaxf(fminf(fmaxf(ax, ay), az), fminf(ax, ay));
    const float x1 = a1 + fh;
    const float d12 = a1 - a2;
    const float disc2 = fh2 + fh2 - d12 * d12;
    const float x2 = 0.5f * (a1 + a2 + sqrtf(fmaxf(disc2, 0.0f)));
    const float s = a1 + a2 + a3;
    const float q = a1 * a1 + a2 * a2 + a3 * a3;
    const float disc3 = s * s - 3.0f * (q - fh2);
    const float x3 = (s + sqrtf(fmaxf(disc3, 0.0f))) * (1.0f / 3.0f);
    const float xv = (x1 <= a2) ? x1 : ((x2 <= a3) ? x2 : x3);
    return fminf(uc, xv);
}

// scope-selected stores (fast=1: plain, stays in the shared same-XCD L2;
// fast=0: sc1 device scope).  FLAT addressing (R7 lesson).
__device__ __forceinline__ void pubD(int* p, int val, int fast) {
    if (fast) asm volatile("global_store_dword %0, %1, off"
                           :: "v"(p), "v"(val) : "memory");
    else      asm volatile("global_store_dword %0, %1, off sc1"
                           :: "v"(p), "v"(val) : "memory");
}
__device__ __forceinline__ void stD(float* p, fx4 v, int fast) {
    if (fast) asm volatile("global_store_dwordx4 %0, %1, off"
                           :: "v"(p), "v"(v) : "memory");
    else      asm volatile("global_store_dwordx4 %0, %1, off sc1"
                           :: "v"(p), "v"(v) : "memory");
}
__device__ __forceinline__ int ldF(const int* p, int fast) {
    int v;
    if (fast) asm volatile("global_load_dword %0, %1, off sc0"
                           : "=&v"(v) : "v"(p) : "memory");
    else      asm volatile("global_load_dword %0, %1, off sc1"
                           : "=&v"(v) : "v"(p) : "memory");
    return v;
}
__device__ __forceinline__ void ldX4(fx4* d, const float* p, int fast) {
    if (fast) asm volatile("global_load_dwordx4 %0, %1, off sc0"
                           : "=&v"(*d) : "v"(p) : "memory");
    else      asm volatile("global_load_dwordx4 %0, %1, off sc1"
                           : "=&v"(*d) : "v"(p) : "memory");
}

// ---------------------------------------------------------------------------
// persistent kernel, plain launch (graph-capturable).  R12: XCD-classified
// per-direction sync.  Theory: the invariant ~5us/round (R0-R11) is fabric
// queueing — every poll/halo/store is device-scope (L2-bypass), and ~4096
// polling waves generate ~0.5+ TB/s of 64B fabric traffic that inflates the
// producer->consumer hop to ~5us.  Fix: z-slab block remap (lin%8 -> slab,
// R6-verified) + per-direction XCC handshake.  Flag value carries producer
// XCC; once a direction is proven same-XCD, its polls go sc0 (shared L2),
// halo loads sc0, data/flag stores plain.  ~89% of interfaces are slab-
// interior -> their whole handshake lives in the XCD's L2 (~60ns, zero
// fabric traffic).  Cross-slab/unknown stay sc1 (R8 behavior, proven).
//
// Deadlock/correctness design (each traced):
//  - one inbox LINE per direction (single writer): no mixed-scope multi-
//    writer line (a dirty L2 copy would mask cross-XCD sc1 updates forever).
//  - poll scope strictly per-direction: a tile with one cross-XCD face must
//    still poll its same-XCD partners via L2 (their stores go plain).
//  - pre-publish always sc1: L3 always holds an xcc-bearing value, so every
//    consumer can classify on its first poll (stale value is monotone-safe).
//  - plain-store/sc1-load same-XCD transient: consumer classifies from the
//    stale L3 flag, switches to sc0 next sample -> progress, not deadlock.
//  - data store scope = AND of its two readers' classifications (row-dir
//    conservative: both y dirs); unstored cells are init-valued everywhere.
// Protocol core unchanged from R8 (flag>=i-1 gates RAW+WAR; per-face
// distance culling; proven absmax 0.5 in R8-R11).
// ---------------------------------------------------------------------------
__global__ __launch_bounds__(256, 4) void eik_persist(float* __restrict__ uA,
                                                      float* __restrict__ uB,
                                                      const float* __restrict__ fP,
                                                      float* __restrict__ out,
                                                      int* __restrict__ inbox) {
    const int tid  = threadIdx.x;      // 0..255
    const int w    = tid >> 6;         // wave 0..3
    const int lane = tid & 63;
    const int r    = lane >> 5;        // row within tile (0/1)
    const int sub  = lane & 31;        // x-group
    const int x0   = sub * 4;

    // physical -> slab-logical remap: slab s owns z-blocks [4s, 4s+4)
    const int lin = blockIdx.y + 32 * blockIdx.z;  // 0..1023
    const int s8  = lin & 7;
    const int t   = lin >> 3;                      // 0..127
    const int byl = t & 31;                        // 0..31
    const int bzl = s8 * 4 + (t >> 5);             // 0..31
    const int ly  = byl * 2 + (w & 1);             // 0..63
    const int lz  = bzl * 2 + (w >> 1);            // 0..63
    const int gy0 = ly * 2;
    const int gz0 = lz * 2;
    const int gy  = gy0 + r;

    int myxcc;
    asm("s_getreg_b32 %0, hwreg(HW_REG_XCC_ID)" : "=s"(myxcc));
    const int myx1 = (myxcc & 0xf) + 1;

    // per-cell act distances
    const int dxm = (x0 <= 64 && 64 <= x0 + 3) ? 0
                                               : min(abs(x0 - 64), abs(x0 + 3 - 64));
    const int dy = abs(gy - 64);
    const int d0 = dxm + dy + abs(gz0 - 64);
    const int d1 = dxm + dy + abs(gz0 + 1 - 64);
    const int dmin01 = min(d0, d1);

    // tile/face distances
    const int dymin = (gy0 > 64) ? (gy0 - 64) : ((gy0 + 1 < 64) ? (64 - (gy0 + 1)) : 0);
    const int dzmin = (gz0 > 64) ? (gz0 - 64) : ((gz0 + 1 < 64) ? (64 - (gz0 + 1)) : 0);
    const int start = max(1, dymin + dzmin);
    const int dYm = abs(gy0 - 64) + dzmin;
    const int dYp = abs(gy0 + 1 - 64) + dzmin;
    const int dZm = abs(gz0 - 64) + dymin;
    const int dZp = abs(gz0 + 1 - 64) + dymin;

    const int idx = lz * NTY + ly;
    const int* q0 = inbox + 0 * LSTR + idx * 16;   // -y producer's line
    const int* q1 = inbox + 1 * LSTR + idx * 16;   // +y
    const int* q2 = inbox + 2 * LSTR + idx * 16;   // -z
    const int* q3 = inbox + 3 * LSTR + idx * 16;   // +z
    int* pYp = inbox + 0 * LSTR + (idx + 1) * 16;      // I am -y producer of idx+1
    int* pYm = inbox + 1 * LSTR + (idx - 1) * 16;      // +y producer of idx-1
    int* pZp = inbox + 2 * LSTR + (idx + NTY) * 16;    // -z producer of idx+NTY
    int* pZm = inbox + 3 * LSTR + (idx - NTY) * 16;    // +z producer of idx-NTY

    // per-direction same-XCD classification (missing dirs preset = same)
    int sYm = (ly == 0);
    int sYp = (ly == NTY - 1);
    int sZm = (lz == 0);
    int sZp = (lz == NTZ - 1);

    if (lane == 0 && start > 1) {   // pre-publish ALWAYS sc1 (seeds L3 w/ xcc)
        const int pv = (myx1 << 16) | (start - 1);
        if (ly < NTY - 1) pubD(pYp, pv, 0);
        if (ly > 0)       pubD(pYm, pv, 0);
        if (lz < NTZ - 1) pubD(pZp, pv, 0);
        if (lz > 0)       pubD(pZm, pv, 0);
    }

    const int base0 = ((gz0 + 1) * PPY + (gy + 1)) * PITCH_Y + x0;
    const int base1 = base0 + PITCH_Z;
    const int rowoff = (r == 0) ? -PITCH_Y : PITCH_Y;

    fx4 c0 = *(const fx4*)(uA + base0);
    fx4 c1 = *(const fx4*)(uA + base1);
    const fx4 f0 = *(const fx4*)(fP + base0);
    const fx4 f1 = *(const fx4*)(fP + base1);
    const fx4 ff0 = f0 * f0;
    const fx4 ff1 = f1 * f1;

    for (int i = start; i <= NITER; ++i) {
        // ---- per-direction scoped poll ----
        const int tgt = i - 1;
        const int tYm = (dYm <= i) ? tgt : -0x40000000;
        const int tYp = (dYp <= i) ? tgt : -0x40000000;
        const int tZm = (dZm <= i) ? tgt : -0x40000000;
        const int tZp = (dZp <= i) ? tgt : -0x40000000;
        for (;;) {
            int v0 = ldF(q0, sYm);
            int v1 = ldF(q1, sYp);
            int v2 = ldF(q2, sZm);
            int v3 = ldF(q3, sZp);
            asm volatile("s_waitcnt vmcnt(0)"
                         : "+v"(v0), "+v"(v1), "+v"(v2), "+v"(v3) :: "memory");
            sYm |= ((v0 >> 16) == myx1);
            sYp |= ((v1 >> 16) == myx1);
            sZm |= ((v2 >> 16) == myx1);
            sZp |= ((v3 >> 16) == myx1);
            const int i0 = v0 & 0xffff, i1 = v1 & 0xffff;
            const int i2 = v2 & 0xffff, i3 = v3 & 0xffff;
            if (i0 >= tYm && i1 >= tYp && i2 >= tZm && i3 >= tZp) break;
            const int lag = max(max(tYm - i0, tYp - i1), max(tZm - i2, tZp - i3));
            if (lag > 2) __builtin_amdgcn_s_sleep(64);   // far from wavefront
            else         __builtin_amdgcn_s_sleep(2);    // near: fast wake
        }

        // ---- in-wave exchanges ----
        fx4 o0, o1;
        o0.x = __shfl_xor(c0.x, 32); o0.y = __shfl_xor(c0.y, 32);
        o0.z = __shfl_xor(c0.z, 32); o0.w = __shfl_xor(c0.w, 32);
        o1.x = __shfl_xor(c1.x, 32); o1.y = __shfl_xor(c1.y, 32);
        o1.z = __shfl_xor(c1.z, 32); o1.w = __shfl_xor(c1.w, 32);
        float xm0 = __shfl_up(c0.w, 1);   if (sub == 0)  xm0 = GBIG;
        float xp0 = __shfl_down(c0.x, 1); if (sub == 31) xp0 = GBIG;
        float xm1 = __shfl_up(c1.w, 1);   if (sub == 0)  xm1 = GBIG;
        float xp1 = __shfl_down(c1.x, 1); if (sub == 31) xp1 = GBIG;

        const int yF = sYm & sYp;   // y-halo load serves both lane-halves

        if (dmin01 <= i) {
            const float* S = (i & 1) ? uA : uB;
            fx4 yh0, yh1, zm, zp;
            ldX4(&yh0, S + base0 + rowoff, yF);
            ldX4(&yh1, S + base1 + rowoff, yF);
            ldX4(&zm,  S + base0 - PITCH_Z, sZm);
            ldX4(&zp,  S + base1 + PITCH_Z, sZp);
            asm volatile("s_waitcnt vmcnt(0)"
                         : "+v"(yh0), "+v"(yh1), "+v"(zm), "+v"(zp) :: "memory");

            const fx4 ya0 = (r == 0) ? yh0 : o0;
            const fx4 yb0 = (r == 0) ? o0  : yh0;
            const fx4 ya1 = (r == 0) ? yh1 : o1;
            const fx4 yb1 = (r == 0) ? o1  : yh1;

            fx4 n0, n1;
            n0.x = eik_solve(fminf(xm0,  c0.y), fminf(ya0.x, yb0.x), fminf(zm.x, c1.x), f0.x, ff0.x, c0.x);
            n0.y = eik_solve(fminf(c0.x, c0.z), fminf(ya0.y, yb0.y), fminf(zm.y, c1.y), f0.y, ff0.y, c0.y);
            n0.z = eik_solve(fminf(c0.y, c0.w), fminf(ya0.z, yb0.z), fminf(zm.z, c1.z), f0.z, ff0.z, c0.z);
            n0.w = eik_solve(fminf(c0.z, xp0),  fminf(ya0.w, yb0.w), fminf(zm.w, c1.w), f0.w, ff0.w, c0.w);
            n1.x = eik_solve(fminf(xm1,  c1.y), fminf(ya1.x, yb1.x), fminf(c0.x, zp.x), f1.x, ff1.x, c1.x);
            n1.y = eik_solve(fminf(c1.x, c1.z), fminf(ya1.y, yb1.y), fminf(c0.y, zp.y), f1.y, ff1.y, c1.y);
            n1.z = eik_solve(fminf(c1.y, c1.w), fminf(ya1.z, yb1.z), fminf(c0.z, zp.z), f1.z, ff1.z, c1.z);
            n1.w = eik_solve(fminf(c1.z, xp1),  fminf(ya1.w, yb1.w), fminf(c0.w, zp.w), f1.w, ff1.w, c1.w);

            if (i < NITER) {
                float* D = (i & 1) ? uB : uA;
                // plane0 read by a y-neighbor (row-dep) and -z; plane1: ... +z
                if (d0 <= i) { c0 = n0; stD(D + base0, c0, yF & sZm); }
                if (d1 <= i) { c1 = n1; stD(D + base1, c1, yF & sZp); }
            } else {
                if (d0 <= i) c0 = n0;
                if (d1 <= i) c1 = n1;
            }
        }

        if (i < NITER) {
            asm volatile("s_waitcnt vmcnt(0)" ::: "memory");  // drain to scope
            if (lane == 0) {
                const int pv = (myx1 << 16) | i;
                if (ly > 0)       pubD(pYm, pv, sYm);
                if (ly < NTY - 1) pubD(pYp, pv, sYp);
                if (lz > 0)       pubD(pZm, pv, sZm);
                if (lz < NTZ - 1) pubD(pZp, pv, sZp);
            }
        }
    }

    // fused extract
    float* o = out + (gz0 * GN + gy) * GN + x0;
    *(fx4*)o = c0;
    *(fx4*)(o + GN * GN) = c1;
}

// ---------------------------------------------------------------------------
// fallback path (proven 128-launch structure) if occupancy check fails
// ---------------------------------------------------------------------------
__global__ __launch_bounds__(256) void eik_step(const float* __restrict__ uin,
                                                const float* __restrict__ fP,
                                                float* __restrict__ uout,
                                                int iter) {
    const int lx = threadIdx.x;
    const int gy = blockIdx.y * 8 + threadIdx.y;
    const int gz = blockIdx.z;
    const int x0 = 4 * lx;
    const int dxm = (x0 <= 64 && 64 <= x0 + 3)
                        ? 0
                        : min(abs(x0 - 64), abs(x0 + 3 - 64));
    const int d = dxm + abs(gy - 64) + abs(gz - 64);
    if (d > iter) return;

    const int y = gy + 1;
    const int z = gz + 1;
    const int base = (z * PPY + y) * PITCH_Y + x0;

    const float4 c  = *(const float4*)(uin + base);
    float xm_s = uin[base - 1];
    float xp_s = uin[base + 4];
    if (lx == 0)  xm_s = GBIG;
    if (lx == 31) xp_s = GBIG;
    const float4 ym = *(const float4*)(uin + base - PITCH_Y);
    const float4 yp = *(const float4*)(uin + base + PITCH_Y);
    const float4 zm = *(const float4*)(uin + base - PITCH_Z);
    const float4 zp = *(const float4*)(uin + base + PITCH_Z);
    const float4 f4 = *(const float4*)(fP + base);

    float4 res;
    res.x = eik_solve(fminf(xm_s, c.y), fminf(ym.x, yp.x), fminf(zm.x, zp.x), f4.x, f4.x * f4.x, c.x);
    res.y = eik_solve(fminf(c.x, c.z), fminf(ym.y, yp.y), fminf(zm.y, zp.y), f4.y, f4.y * f4.y, c.y);
    res.z = eik_solve(fminf(c.y, c.w), fminf(ym.z, yp.z), fminf(zm.z, zp.z), f4.z, f4.z * f4.z, c.z);
    res.w = eik_solve(fminf(c.z, xp_s), fminf(ym.w, yp.w), fminf(zm.w, zp.w), f4.w, f4.w * f4.w, c.w);

    *(float4*)(uout + base) = res;
}

__global__ __launch_bounds__(256) void eik_extract(const float* __restrict__ uf,
                                                   float* __restrict__ out) {
    const int j = blockIdx.x * 256 + threadIdx.x;
    const int x4 = j & 31;
    const int y  = (j >> 5) & 127;
    const int z  = j >> 12;
    const float4 v =
        *(const float4*)(uf + ((z + 1) * PPY + (y + 1)) * PITCH_Y + 4 * x4);
    *(float4*)(out + 4 * j) = v;
}

extern "C" void kernel_launch(void* const* d_in, const int* in_sizes, int n_in,
                              void* d_out, int out_size, void* d_ws, size_t ws_size,
                              hipStream_t stream) {
    const float* u0 = (const float*)d_in[0];
    const float* f  = (const float*)d_in[1];
    float* out = (float*)d_out;

    float* uA = (float*)d_ws;                    // 8.65 MB each
    float* uB = uA + PADDED_TOTAL;
    float* fP = uB + PADDED_TOTAL;
    int* inbox = (int*)(fP + PADDED_TOTAL);      // 1 MB: 4 direction-planes

    {
        const int nb = (PADDED_TOTAL + 255) / 256;
        eik_init<<<nb, 256, 0, stream>>>(u0, f, uA, uB, fP, inbox);
    }

    // Co-residency capacity check (host query, capture-safe, cached):
    // 1024 blocks / 256 CUs -> need >= 4 blocks/CU resident.
    static int resident_ok = -1;
    if (resident_ok < 0) {
        int maxb = 0;
        hipError_t qe =
            hipOccupancyMaxActiveBlocksPerMultiprocessor(&maxb, eik_persist, 256, 0);
        resident_ok = (qe == hipSuccess && maxb >= 4) ? 1 : 0;
    }

    if (resident_ok) {
        eik_persist<<<dim3(1, 32, 32), 256, 0, stream>>>(uA, uB, fP, out, inbox);
        return;
    }

    // fallback: proven 128-launch ping-pong
    const dim3 block(32, 8, 1);
    const dim3 grid(1, 16, 128);
    for (int i = 1; i <= NITER; ++i) {
        const float* in = (i & 1) ? uA : uB;
        float* o        = (i & 1) ? uB : uA;
        eik_step<<<grid, block, 0, stream>>>(in, fP, o, i);
    }
    eik_extract<<<GN * GN * GN / 4 / 256, 256, 0, stream>>>(uA, out);
}